// Round 5
// baseline (292.456 us; speedup 1.0000x reference)
//
#include <hip/hip_runtime.h>

// NCC loss: 1 - mean( cross^2 / (pvar*tvar + 1e-8) ) over 9^3 zero-padded
// box windows, input (4,1,160,160,160) fp32.
//
// R10: model recalibration — VALUBusy ~44% is "any-SIMD busy" (~12% true
// issue), so the kernel is per-step LATENCY-bound: 40 barriers/block, each
// exposing prefetch-drain latency at __syncthreads (R8 proved hand barriers
// are worse). R10 = fewer, fatter steps: 20 DOUBLE-steps, each
//   [issue BOTH slices' loads back-to-back] -> update/stage slice A ->
//   update/stage slice B -> ONE barrier -> red wave reduces A and B.
// Loads are consumed mid-step (vmcnt hits 0 naturally; the barrier drain is
// free), latencies of the two slices overlap, barrier count halves, and the
// persistent cross-barrier prefetch regs (pa4/ta4) are GONE -> register
// pressure drops (~154/wave vs ~170), helping the 2-3 block/CU residency cap.
// LDS: 2 pairs of staging buffers (A,B double-buffered) = 38.4 KB.
// Keeps R9's dedicated reduction wave (BLK=256, tid>=192).

#define DSZ    160
#define NBATCH 4
#define RAD    4
#define TX     16
#define TY     16
#define ZCHUNK 40
#define SLICE  (DSZ*DSZ)
#define VOL    (DSZ*DSZ*DSZ)
#define WINV   (1.0f/729.0f)
#define NVOX_INV (1.0f/16384000.0f)

#define NROW 24        // halo rows per tile
#define NGRP 6         // x groups of 4 halo cols (24)
#define BLK  256       // 3 staging waves (tid<192) + 1 reduction wave

#define S2_RS 20                 // row stride: 16 outputs + pad (2-way banks)
#define S2_FS (NROW*S2_RS)       // 480 floats per field
#define S2_BUF (5*S2_FS)         // 2400 floats per staging buffer

__device__ __forceinline__ float dpp_shl1(float x) {  // lane i <- lane i+1 (16-lane row, OOB=0)
    return __int_as_float(__builtin_amdgcn_update_dpp(0, __float_as_int(x), 0x101, 0xf, 0xf, true));
}
__device__ __forceinline__ float dpp_shl2(float x) {  // lane i <- lane i+2
    return __int_as_float(__builtin_amdgcn_update_dpp(0, __float_as_int(x), 0x102, 0xf, 0xf, true));
}

__global__ __launch_bounds__(BLK, 3)
void ncc_main(const float* __restrict__ pred, const float* __restrict__ tgt,
              float* __restrict__ accum)
{
    const int tid = threadIdx.x;
    const int row = tid >> 3;      // 0..23 halo row (staging threads)
    const int g   = tid & 7;       // 0..7; g<6 = active x-group
    const int ox  = blockIdx.x * TX;
    const int oy  = blockIdx.y * TY;
    const int batch = blockIdx.z >> 2;
    const int z0  = (blockIdx.z & 3) * ZCHUNK;

    __shared__ float s2[4*S2_BUF];   // 38.4 KB: 2 double-buffered pairs (A,B)

    const bool stg = (tid < 192) && (g < NGRP);
    const bool red = (tid >= 192);               // dedicated reduction wave
    const int  gy  = oy - RAD + row;
    const int  gx0 = ox - RAD + g*4;
    const bool ldok = stg && (gy >= 0) && (gy < DSZ) && (gx0 >= 0) && (gx0 + 3 < DSZ);
    const int  base = batch*VOL + gy*DSZ + gx0;     // only used under ldok

    // register ring of raw slice values (own 4 columns), chunk-local slots
    float rp[9][4], rt[9][4];
    float zs[5][4];
    #pragma unroll
    for (int k = 0; k < 9; ++k)
        #pragma unroll
        for (int j = 0; j < 4; ++j) { rp[k][j] = 0.f; rt[k][j] = 0.f; }
    #pragma unroll
    for (int f = 0; f < 5; ++f)
        #pragma unroll
        for (int j = 0; j < 4; ++j) zs[f][j] = 0.f;

    // ---- warm-up: chunk-local slices 0..7 (z = z0-4 .. z0+3) -> slots 0..7
    if (stg) {
        #pragma unroll
        for (int i = 0; i < 8; ++i) {
            int z = z0 - RAD + i;
            if (z >= 0) {                       // uniform; z < DSZ always here
                float4 p4 = {0,0,0,0}, t4 = {0,0,0,0};
                if (ldok) {
                    p4 = *(const float4*)(pred + base + z*SLICE);
                    t4 = *(const float4*)(tgt  + base + z*SLICE);
                }
                const float pc[4] = {p4.x,p4.y,p4.z,p4.w};
                const float tc[4] = {t4.x,t4.y,t4.z,t4.w};
                #pragma unroll
                for (int j = 0; j < 4; ++j) {
                    zs[0][j] += pc[j];        zs[1][j] += tc[j];
                    zs[2][j] += pc[j]*pc[j];  zs[3][j] += tc[j]*tc[j];
                    zs[4][j] += pc[j]*tc[j];
                    rp[i][j] = pc[j];  rt[i][j] = tc[j];
                }
            }
        }
    }

    int za = z0 + RAD;                      // absolute z of next slice to eat
    int zmax = z0 + ZCHUNK + RAD;           // last useful slice + 1
    if (zmax > DSZ) zmax = DSZ;

    int pb = 1;          // pair toggle (first double-step -> pair 0)
    float acc = 0.f;

// per-slice staging work: ring/zs update + x-prefix + LDS write
#define PROC(SLOT, P4, T4, DST) do {                                          \
    const float pc[4] = {P4.x,P4.y,P4.z,P4.w};                                \
    const float tc[4] = {T4.x,T4.y,T4.z,T4.w};                                \
    _Pragma("unroll")                                                         \
    for (int j = 0; j < 4; ++j) {                                             \
        float ps = rp[SLOT][j], qs = rt[SLOT][j];                             \
        float d0 = pc[j] - ps, d1 = tc[j] - qs;                               \
        zs[0][j] += d0;                                                       \
        zs[1][j] += d1;                                                       \
        zs[2][j] += d0*(pc[j] + ps);                                          \
        zs[3][j] += d1*(tc[j] + qs);                                          \
        zs[4][j] += pc[j]*tc[j] - ps*qs;                                      \
        rp[SLOT][j] = pc[j];  rt[SLOT][j] = tc[j];                            \
    }                                                                         \
    _Pragma("unroll")                                                         \
    for (int f = 0; f < 5; ++f) {                                             \
        float P0 = zs[f][0];                                                  \
        float P1 = P0 + zs[f][1];                                             \
        float P2 = P1 + zs[f][2];                                             \
        float P3 = P2 + zs[f][3];                                             \
        float T  = dpp_shl1(P3);                                              \
        float Q0 = dpp_shl2(P0), Q1 = dpp_shl2(P1);                           \
        float Q2 = dpp_shl2(P2), Q3 = dpp_shl2(P3);                           \
        if (g < 4) {                                                          \
            float b = P3 + T;                                                 \
            float* dst = &(DST)[f*S2_FS + row*S2_RS + g*4];                   \
            dst[0] = b + Q0;                                                  \
            dst[1] = b - P0 + Q1;                                             \
            dst[2] = b - P1 + Q2;                                             \
            dst[3] = b - P2 + Q3;                                             \
        }                                                                     \
    }                                                                         \
} while (0)

// 9-tap y-box reduction + cc epilogue over one staged buffer
#define REDUCE(SRC) do {                                                      \
    const int x = tid & 15, yq = ((tid >> 4) & 3)*4;                          \
    float S[5][4];                                                            \
    _Pragma("unroll")                                                         \
    for (int f = 0; f < 5; ++f) {                                             \
        const float* col = &(SRC)[f*S2_FS + x];                               \
        float r0 = col[(yq+0)*S2_RS], r1 = col[(yq+1)*S2_RS];                 \
        float r2 = col[(yq+2)*S2_RS], r3 = col[(yq+3)*S2_RS];                 \
        float run = r0+r1+r2+r3 + col[(yq+4)*S2_RS] + col[(yq+5)*S2_RS]       \
                  + col[(yq+6)*S2_RS] + col[(yq+7)*S2_RS];                    \
        run += col[(yq+8)*S2_RS];        S[f][0] = run;                       \
        run += col[(yq+9)*S2_RS]  - r0;  S[f][1] = run;                       \
        run += col[(yq+10)*S2_RS] - r1;  S[f][2] = run;                       \
        run += col[(yq+11)*S2_RS] - r2;  S[f][3] = run;                       \
    }                                                                         \
    _Pragma("unroll")                                                         \
    for (int i = 0; i < 4; ++i) {                                             \
        float Sp = S[0][i], St = S[1][i];                                     \
        float cross = S[4][i] - Sp*St*WINV;                                   \
        float pv    = S[2][i] - Sp*Sp*WINV;                                   \
        float tv    = S[3][i] - St*St*WINV;                                   \
        acc += cross*cross / (pv*tv + 1e-8f);                                 \
    }                                                                         \
} while (0)

// one double-step: 2 slices, 1 barrier
#define NCC2(SA, SB) do {                                                     \
    pb ^= 1;                                                                  \
    float* bufA = s2 + pb*2*S2_BUF;                                           \
    float* bufB = bufA + S2_BUF;                                              \
    if (stg) {                                                                \
        float4 p0={0,0,0,0}, t0={0,0,0,0}, p1={0,0,0,0}, t1={0,0,0,0};        \
        if (ldok) {                                                           \
            if (za < zmax) {                                                  \
                p0 = *(const float4*)(pred + base + za*SLICE);                \
                t0 = *(const float4*)(tgt  + base + za*SLICE);                \
            }                                                                 \
            if (za+1 < zmax) {                                                \
                p1 = *(const float4*)(pred + base + (za+1)*SLICE);            \
                t1 = *(const float4*)(tgt  + base + (za+1)*SLICE);            \
            }                                                                 \
        }                                                                     \
        za += 2;                                                              \
        PROC(SA, p0, t0, bufA);                                               \
        PROC(SB, p1, t1, bufB);                                               \
    }                                                                         \
    __syncthreads();                                                          \
    if (red) { REDUCE(bufA); REDUCE(bufB); }                                  \
} while (0)

    // double-step u consumes slices (2u, 2u+1) after z0+RAD-  ; ring slots
    // (2u+8)%9, (2u+9)%9 — period 9 double-steps. 20 = 2 + 2*9.
    NCC2(8,0); NCC2(1,2);
    for (int it = 0; it < 2; ++it) {
        NCC2(3,4); NCC2(5,6); NCC2(7,8);
        NCC2(0,1); NCC2(2,3); NCC2(4,5);
        NCC2(6,7); NCC2(8,0); NCC2(1,2);
    }
#undef NCC2
#undef REDUCE
#undef PROC

    // all cc partials live in the reduction wave (tid 192..255)
    if (red) {
        float v = acc;
        #pragma unroll
        for (int off = 32; off > 0; off >>= 1) v += __shfl_down(v, off, 64);
        if (tid == 192) atomicAdd(accum, v);
    }
}

__global__ void ncc_final(const float* __restrict__ accum, float* __restrict__ out)
{
    out[0] = 1.0f - accum[0] * NVOX_INV;
}

extern "C" void kernel_launch(void* const* d_in, const int* in_sizes, int n_in,
                              void* d_out, int out_size, void* d_ws, size_t ws_size,
                              hipStream_t stream)
{
    const float* pred = (const float*)d_in[0];
    const float* tgt  = (const float*)d_in[1];
    float* out = (float*)d_out;
    float* ws  = (float*)d_ws;

    hipMemsetAsync(ws, 0, sizeof(float), stream);
    dim3 grid(DSZ/TX, DSZ/TY, NBATCH*4);   // 10 x 10 x 16 = 1600 blocks
    ncc_main<<<grid, BLK, 0, stream>>>(pred, tgt, ws);
    ncc_final<<<1, 1, 0, stream>>>(ws, out);
}